// Round 7
// baseline (82.553 us; speedup 1.0000x reference)
//
#include <hip/hip_runtime.h>
#include <math.h>

#define BLOCK 256

__device__ __forceinline__ float fast_rcp(float x) {
    return __builtin_amdgcn_rcpf(x);
}
// HW sin/cos: v_sin_f32/v_cos_f32 take revolutions; |arg| < 1 rev here -> full accuracy
__device__ __forceinline__ float fsin(float x) {
    return __builtin_amdgcn_sinf(x * 0.15915494309189535f);
}
__device__ __forceinline__ float fcos(float x) {
    return __builtin_amdgcn_cosf(x * 0.15915494309189535f);
}

// L1 "diamond" pseudo-angle: strictly monotone in atan2(y,x); (0,0) -> 0.
__device__ __forceinline__ float pseudo_angle(float x, float y) {
    float d = fabsf(x) + fabsf(y);
    float p = (d == 0.f) ? 1.f : x * fast_rcp(d);
    return (y < 0.f) ? (p - 1.f) : (1.f - p);
}

// Running-shoelace state: first point, prev point, accumulator.
struct Shoe {
    float sfx, sfy, spx, spy, acc;
    bool have;
};

__device__ __forceinline__ void emit(Shoe& s, bool c, float X, float Y) {
    float cr = s.spx * Y - s.spy * X;
    s.acc += (c && s.have) ? cr : 0.f;
    s.sfx = (c && !s.have) ? X : s.sfx;
    s.sfy = (c && !s.have) ? Y : s.sfy;
    s.spx = c ? X : s.spx;
    s.spy = c ? Y : s.spy;
    s.have = s.have || c;
}

// SH edge (a->b) clipped against y in [-hh, hh], emissions into running shoelace.
__device__ __forceinline__ void edge_clip_y(Shoe& s, bool en, float ax, float ay,
                                            float bx, float by, float hh) {
    bool inA = en && (ay <= hh) && (ay >= -hh);
    bool cA = en && ((ay > hh) != (by > hh));
    bool cB = en && ((ay < -hh) != (by < -hh));
    float dxe = bx - ax, dye = by - ay;
    float rd = fast_rcp(dye);
    float tA = (hh - ay) * rd;
    float tB = (-hh - ay) * rd;
    float xA = fmaf(tA, dxe, ax);
    float xB = fmaf(tB, dxe, ax);
    bool fA = cA && (!cB || (tA <= tB));
    float e1x = fA ? xA : xB, e1y = fA ? hh : -hh;
    float e2x = fA ? xB : xA, e2y = fA ? -hh : hh;
    emit(s, inA, ax, ay);
    emit(s, cA || cB, e1x, e1y);
    emit(s, cA && cB, e2x, e2y);
}

// Full per-box GIoU loss (weighted), everything in registers.
__device__ __forceinline__ float box_loss(const float* __restrict__ pred,
                                          const float* __restrict__ target,
                                          const float* __restrict__ weight, int i) {
    float p[5], q[5];
#pragma unroll
    for (int j = 0; j < 5; ++j) p[j] = pred[i * 5 + j];
#pragma unroll
    for (int j = 0; j < 5; ++j) q[j] = target[i * 5 + j];
    float wgt = weight[i];

    // ---- box2's local frame (areas rotation-invariant) ----
    float cq = fcos(q[4]), sq = fsin(q[4]);
    float dang = p[4] - q[4];
    float cd = fcos(dang), sd = fsin(dang);
    float hw = 0.5f * q[2], hh = 0.5f * q[3];   // box2 = [-hw,hw]x[-hh,hh]
    float dxc = p[0] - q[0], dyc = p[1] - q[1];
    float tx = dxc * cq + dyc * sq;
    float ty = -dxc * sq + dyc * cq;
    float ax_ = 0.5f * p[2] * cd, ay_ = 0.5f * p[2] * sd;
    float bx_ = -0.5f * p[3] * sd, by_ = 0.5f * p[3] * cd;

    float qx[4], qy[4];
    qx[0] = tx + ax_ + bx_; qy[0] = ty + ay_ + by_;
    qx[1] = tx - ax_ + bx_; qy[1] = ty - ay_ + by_;
    qx[2] = tx - ax_ - bx_; qy[2] = ty - ay_ - by_;
    qx[3] = tx + ax_ - bx_; qy[3] = ty + ay_ - by_;

    // ---- slab 1: clip quad against x in [-hw, hw] -> 8 fixed register slots ----
    float sxk[8], syk[8];
    bool sv[8];
#pragma unroll
    for (int e = 0; e < 4; ++e) {
        int en = (e + 1) & 3;
        float xc = qx[e], yc = qy[e], xn = qx[en], yn = qy[en];
        float dxe = xn - xc, dye = yn - yc;
        bool inC = (xc <= hw) && (xc >= -hw);
        bool cA = (xc > hw) != (xn > hw);
        bool cB = (xc < -hw) != (xn < -hw);
        float rd = fast_rcp(dxe);
        float tA = (hw - xc) * rd;
        float tB = (-hw - xc) * rd;
        float yA = fmaf(tA, dye, yc);
        float yB = fmaf(tB, dye, yc);
        bool fA = cA && (!cB || (tA <= tB));
        float X1x = fA ? hw : -hw, X1y = fA ? yA : yB;
        float X2x = fA ? -hw : hw, X2y = fA ? yB : yA;
        sxk[2 * e]     = inC ? xc : X1x;
        syk[2 * e]     = inC ? yc : X1y;
        sv[2 * e]      = inC || cA || cB;
        sxk[2 * e + 1] = inC ? X1x : X2x;
        syk[2 * e + 1] = inC ? X1y : X2y;
        sv[2 * e + 1]  = inC ? (cA || cB) : (cA && cB);
    }

    // ---- slab 2 (y in [-hh,hh]) fused with running shoelace ----
    Shoe sh; sh.sfx = sh.sfy = sh.spx = sh.spy = sh.acc = 0.f; sh.have = false;
    bool have_p = false;
    float pfx = 0.f, pfy = 0.f, pvx = 0.f, pvy = 0.f;
#pragma unroll
    for (int k = 0; k < 8; ++k) {
        bool val = sv[k];
        float cx_ = sxk[k], cy_ = syk[k];
        edge_clip_y(sh, have_p && val, pvx, pvy, cx_, cy_, hh);
        pfx = (val && !have_p) ? cx_ : pfx;
        pfy = (val && !have_p) ? cy_ : pfy;
        pvx = val ? cx_ : pvx;
        pvy = val ? cy_ : pvy;
        have_p = have_p || val;
    }
    edge_clip_y(sh, have_p, pvx, pvy, pfx, pfy, hh);   // wrap edge
    float wrap = sh.spx * sh.sfy - sh.spy * sh.sfx;
    float accs = sh.acc + (sh.have ? wrap : 0.f);
    float overlap = 0.5f * fabsf(accs);

    // ---- enclose: 8 frame points, angle-sorted shoelace via Batcher-19 network ----
    float enc;
    {
        float px8[8], py8[8];
#pragma unroll
        for (int j = 0; j < 4; ++j) { px8[j] = qx[j]; py8[j] = qy[j]; }
        px8[4] = hw;  py8[4] = hh;
        px8[5] = -hw; py8[5] = hh;
        px8[6] = -hw; py8[6] = -hh;
        px8[7] = hw;  py8[7] = -hh;
        float ex = 0.f, ey = 0.f;
#pragma unroll
        for (int j = 0; j < 8; ++j) { ex += px8[j]; ey += py8[j]; }
        float mx = ex * 0.125f, my = ey * 0.125f;
        float ang[8];
#pragma unroll
        for (int j = 0; j < 8; ++j) ang[j] = pseudo_angle(px8[j] - mx, py8[j] - my);

        // Batcher odd-even merge sort, 8 inputs, 19 compare-exchanges.
        // (ties in pseudo-angle are measure-zero on random data)
#define CE(I, J)                                                   \
        {                                                          \
            bool sw = ang[I] > ang[J];                             \
            float ta = sw ? ang[J] : ang[I];                       \
            float tb = sw ? ang[I] : ang[J];                       \
            ang[I] = ta; ang[J] = tb;                              \
            float txp = sw ? px8[J] : px8[I];                      \
            float typ = sw ? py8[J] : py8[I];                      \
            px8[J] = sw ? px8[I] : px8[J];                         \
            py8[J] = sw ? py8[I] : py8[J];                         \
            px8[I] = txp; py8[I] = typ;                            \
        }
        CE(0,1) CE(2,3) CE(4,5) CE(6,7)
        CE(0,2) CE(1,3) CE(4,6) CE(5,7)
        CE(1,2) CE(5,6)
        CE(0,4) CE(1,5) CE(2,6) CE(3,7)
        CE(2,4) CE(3,5)
        CE(1,2) CE(3,4) CE(5,6)
#undef CE

        float acc2 = 0.f;
#pragma unroll
        for (int k = 0; k < 8; ++k) {
            int kn = (k + 1) & 7;
            acc2 += px8[k] * py8[kn] - py8[k] * px8[kn];
        }
        enc = 0.5f * fabsf(acc2);
    }

    // ---- GIoU loss ----
    float area1 = p[2] * p[3];
    float area2 = q[2] * q[3];
    float uni = area1 + area2 - overlap + 1e-6f;
    float iou = fmaxf(overlap / uni, 1e-6f);
    float giou = iou - (enc - uni) / enc;
    return (1.f - giou) * wgt;
}

__launch_bounds__(BLOCK)
__global__ void giou_kernel(const float* __restrict__ pred,
                            const float* __restrict__ target,
                            const float* __restrict__ weight,
                            float* __restrict__ partials, int N, int half) {
    // TWO boxes per thread (i and i+half): two independent dependency chains
    // per lane -> ~2x VALU issue density in the select-chain regions.
    int tid = threadIdx.x;
    int gi = blockIdx.x * BLOCK + tid;
    int i1 = (gi < half) ? gi : (half - 1);
    int i2 = i1 + half;
    bool v1 = (gi < half);
    bool v2 = v1 && (i2 < N);
    i2 = v2 ? i2 : i1;

    float l1 = box_loss(pred, target, weight, i1);
    float l2 = box_loss(pred, target, weight, i2);
    float loss = (v1 ? l1 : 0.f) + (v2 ? l2 : 0.f);

    // wave-64 reduce -> one plain store per wave (no global atomics)
#pragma unroll
    for (int off = 32; off > 0; off >>= 1)
        loss += __shfl_down(loss, off, 64);
    if ((tid & 63) == 0)
        partials[blockIdx.x * (BLOCK / 64) + (tid >> 6)] = loss;
}

// Deterministic final reduce: one 1024-thread block over the partials.
__launch_bounds__(1024)
__global__ void reduce_kernel(const float* __restrict__ partials,
                              float* __restrict__ out, int nparts, float scale) {
    __shared__ float acc[16];
    int tid = threadIdx.x;
    float s = 0.f;
    for (int j = tid; j < nparts; j += 1024) s += partials[j];
#pragma unroll
    for (int off = 32; off > 0; off >>= 1)
        s += __shfl_down(s, off, 64);
    if ((tid & 63) == 0) acc[tid >> 6] = s;
    __syncthreads();
    if (tid == 0) {
        float t = 0.f;
#pragma unroll
        for (int k = 0; k < 16; ++k) t += acc[k];
        out[0] = t * scale;
    }
}

extern "C" void kernel_launch(void* const* d_in, const int* in_sizes, int n_in,
                              void* d_out, int out_size, void* d_ws, size_t ws_size,
                              hipStream_t stream) {
    const float* pred   = (const float*)d_in[0];
    const float* target = (const float*)d_in[1];
    const float* weight = (const float*)d_in[2];
    float* out = (float*)d_out;
    float* ws  = (float*)d_ws;
    int N = in_sizes[0] / 5;
    int half = (N + 1) / 2;

    int nblocks = (half + BLOCK - 1) / BLOCK;
    int nparts = nblocks * (BLOCK / 64);
    giou_kernel<<<nblocks, BLOCK, 0, stream>>>(pred, target, weight, ws, N, half);
    reduce_kernel<<<1, 1024, 0, stream>>>(ws, out, nparts, 1.0f / (float)N);
}

// Round 8
// 82.311 us; speedup vs baseline: 1.0029x; 1.0029x over previous
//
#include <hip/hip_runtime.h>
#include <math.h>

#define BLOCK 256

__device__ __forceinline__ float fast_rcp(float x) {
    return __builtin_amdgcn_rcpf(x);
}
__device__ __forceinline__ float fsin(float x) {
    return __builtin_amdgcn_sinf(x * 0.15915494309189535f);
}
__device__ __forceinline__ float fcos(float x) {
    return __builtin_amdgcn_cosf(x * 0.15915494309189535f);
}

// L1 "diamond" pseudo-angle: strictly monotone in atan2(y,x); (0,0) -> 0.
__device__ __forceinline__ float pseudo_angle(float x, float y) {
    float d = fabsf(x) + fabsf(y);
    float p = (d == 0.f) ? 1.f : x * fast_rcp(d);
    return (y < 0.f) ? (p - 1.f) : (1.f - p);
}

// Liang-Barsky clip of segment a->b against AABB [-hw,hw]x[-hh,hh];
// returns cross(pa,pb) of the clipped sub-segment (0 if empty).
// Fully independent chain, no carried state.
__device__ __forceinline__ float seg_in_aabb_cross(float ax, float ay,
                                                   float bx, float by,
                                                   float hw, float hh) {
    float ex = bx - ax, ey = by - ay;
    float t0 = 0.f, t1 = 1.f;
    bool feas = true;
    {
        bool par = (ex == 0.f);
        float r = fast_rcp(ex);
        float ta = (hw - ax) * r, tb = (-hw - ax) * r;
        float tlo = fminf(ta, tb), thi = fmaxf(ta, tb);
        t0 = par ? t0 : fmaxf(t0, tlo);
        t1 = par ? t1 : fminf(t1, thi);
        feas = feas && (!par || (fabsf(ax) <= hw));
    }
    {
        bool par = (ey == 0.f);
        float r = fast_rcp(ey);
        float ta = (hh - ay) * r, tb = (-hh - ay) * r;
        float tlo = fminf(ta, tb), thi = fmaxf(ta, tb);
        t0 = par ? t0 : fmaxf(t0, tlo);
        t1 = par ? t1 : fminf(t1, thi);
        feas = feas && (!par || (fabsf(ay) <= hh));
    }
    bool valid = feas && (t1 > t0);
    float pax = fmaf(t0, ex, ax), pay = fmaf(t0, ey, ay);
    float pbx = fmaf(t1, ex, ax), pby = fmaf(t1, ey, ay);
    float cr = pax * pby - pay * pbx;
    return valid ? cr : 0.f;
}

// Clip segment a + t*e (t in [0,1]) against CCW convex quad (qx,qy);
// inside: cross(d_i, p - v_i) >= 0. Returns cross(pa,pb) of clipped part.
__device__ __forceinline__ float seg_in_quad_cross(float ax, float ay,
                                                   float ex, float ey,
                                                   const float* qx,
                                                   const float* qy) {
    float t0 = 0.f, t1 = 1.f;
    bool feas = true;
#pragma unroll
    for (int i = 0; i < 4; ++i) {
        int in_ = (i + 1) & 3;
        float dix = qx[in_] - qx[i], diy = qy[in_] - qy[i];
        float ga = dix * (ay - qy[i]) - diy * (ax - qx[i]);  // g(0)
        float gd = dix * ey - diy * ex;                      // dg/dt
        bool par = (gd == 0.f);
        float tk = -ga * fast_rcp(gd);
        t0 = (!par && gd > 0.f) ? fmaxf(t0, tk) : t0;
        t1 = (!par && gd < 0.f) ? fminf(t1, tk) : t1;
        feas = feas && (!par || (ga >= 0.f));
    }
    bool valid = feas && (t1 > t0);
    float pax = fmaf(t0, ex, ax), pay = fmaf(t0, ey, ay);
    float pbx = fmaf(t1, ex, ax), pby = fmaf(t1, ey, ay);
    float cr = pax * pby - pay * pbx;
    return valid ? cr : 0.f;
}

__launch_bounds__(BLOCK)
__global__ void giou_kernel(const float* __restrict__ pred,
                            const float* __restrict__ target,
                            const float* __restrict__ weight,
                            float* __restrict__ partials, int N) {
    int tid = threadIdx.x;
    long gi = (long)blockIdx.x * BLOCK + tid;
    int i = (gi < (long)N) ? (int)gi : (N - 1);

    float p[5], q[5];
#pragma unroll
    for (int j = 0; j < 5; ++j) p[j] = pred[i * 5 + j];
#pragma unroll
    for (int j = 0; j < 5; ++j) q[j] = target[i * 5 + j];
    float wgt = weight[i];

    // ---- box2's local frame (areas rotation-invariant) ----
    float cq = fcos(q[4]), sq = fsin(q[4]);
    float dang = p[4] - q[4];
    float cd = fcos(dang), sd = fsin(dang);
    float hw = 0.5f * q[2], hh = 0.5f * q[3];   // box2 = [-hw,hw]x[-hh,hh]
    float dxc = p[0] - q[0], dyc = p[1] - q[1];
    float tx = dxc * cq + dyc * sq;
    float ty = -dxc * sq + dyc * cq;
    float ax_ = 0.5f * p[2] * cd, ay_ = 0.5f * p[2] * sd;
    float bx_ = -0.5f * p[3] * sd, by_ = 0.5f * p[3] * cd;

    // box1 corners in frame, CCW (verified: shoelace > 0)
    float qx[4], qy[4];
    qx[0] = tx + ax_ + bx_; qy[0] = ty + ay_ + by_;
    qx[1] = tx - ax_ + bx_; qy[1] = ty - ay_ + by_;
    qx[2] = tx - ax_ - bx_; qy[2] = ty - ay_ - by_;
    qx[3] = tx + ax_ - bx_; qy[3] = ty + ay_ - by_;

    // ---- overlap via Green's theorem: 8 INDEPENDENT segment clips ----
    // boundary(P∩Q) = (P edges ∩ AABB) ∪ (AABB edges ∩ P), all CCW.
    float s = 0.f;
    // P edges clipped to AABB
    s += seg_in_aabb_cross(qx[0], qy[0], qx[1], qy[1], hw, hh);
    s += seg_in_aabb_cross(qx[1], qy[1], qx[2], qy[2], hw, hh);
    s += seg_in_aabb_cross(qx[2], qy[2], qx[3], qy[3], hw, hh);
    s += seg_in_aabb_cross(qx[3], qy[3], qx[0], qy[0], hw, hh);
    // AABB edges (CCW: (hw,-hh)->(hw,hh)->(-hw,hh)->(-hw,-hh)->) clipped to P
    float w2 = hw + hw, h2 = hh + hh;
    s += seg_in_quad_cross(hw, -hh, 0.f, h2, qx, qy);    // right, up
    s += seg_in_quad_cross(hw, hh, -w2, 0.f, qx, qy);    // top, left
    s += seg_in_quad_cross(-hw, hh, 0.f, -h2, qx, qy);   // left, down
    s += seg_in_quad_cross(-hw, -hh, w2, 0.f, qx, qy);   // bottom, right
    float overlap = 0.5f * fabsf(s);

    // ---- enclose: 8 frame points, angle-sorted shoelace via Batcher-19 ----
    float enc;
    {
        float px8[8], py8[8];
#pragma unroll
        for (int j = 0; j < 4; ++j) { px8[j] = qx[j]; py8[j] = qy[j]; }
        px8[4] = hw;  py8[4] = hh;
        px8[5] = -hw; py8[5] = hh;
        px8[6] = -hw; py8[6] = -hh;
        px8[7] = hw;  py8[7] = -hh;
        float ex = 0.f, ey = 0.f;
#pragma unroll
        for (int j = 0; j < 8; ++j) { ex += px8[j]; ey += py8[j]; }
        float mx = ex * 0.125f, my = ey * 0.125f;
        float ang[8];
#pragma unroll
        for (int j = 0; j < 8; ++j) ang[j] = pseudo_angle(px8[j] - mx, py8[j] - my);

#define CE(I, J)                                                   \
        {                                                          \
            bool sw = ang[I] > ang[J];                             \
            float ta = sw ? ang[J] : ang[I];                       \
            float tb = sw ? ang[I] : ang[J];                       \
            ang[I] = ta; ang[J] = tb;                              \
            float txp = sw ? px8[J] : px8[I];                      \
            float typ = sw ? py8[J] : py8[I];                      \
            px8[J] = sw ? px8[I] : px8[J];                         \
            py8[J] = sw ? py8[I] : py8[J];                         \
            px8[I] = txp; py8[I] = typ;                            \
        }
        CE(0,1) CE(2,3) CE(4,5) CE(6,7)
        CE(0,2) CE(1,3) CE(4,6) CE(5,7)
        CE(1,2) CE(5,6)
        CE(0,4) CE(1,5) CE(2,6) CE(3,7)
        CE(2,4) CE(3,5)
        CE(1,2) CE(3,4) CE(5,6)
#undef CE

        float acc2 = 0.f;
#pragma unroll
        for (int k = 0; k < 8; ++k) {
            int kn = (k + 1) & 7;
            acc2 += px8[k] * py8[kn] - py8[k] * px8[kn];
        }
        enc = 0.5f * fabsf(acc2);
    }

    // ---- GIoU loss ----
    float area1 = p[2] * p[3];
    float area2 = q[2] * q[3];
    float uni = area1 + area2 - overlap + 1e-6f;
    float iou = fmaxf(overlap / uni, 1e-6f);
    float giou = iou - (enc - uni) / enc;
    float loss = (1.f - giou) * wgt;
    if (gi >= (long)N) loss = 0.f;

    // wave-64 reduce -> one plain store per wave (no global atomics)
#pragma unroll
    for (int off = 32; off > 0; off >>= 1)
        loss += __shfl_down(loss, off, 64);
    if ((tid & 63) == 0)
        partials[blockIdx.x * (BLOCK / 64) + (tid >> 6)] = loss;
}

// Deterministic final reduce: one 1024-thread block over the partials.
__launch_bounds__(1024)
__global__ void reduce_kernel(const float* __restrict__ partials,
                              float* __restrict__ out, int nparts, float scale) {
    __shared__ float acc[16];
    int tid = threadIdx.x;
    float s = 0.f;
    for (int j = tid; j < nparts; j += 1024) s += partials[j];
#pragma unroll
    for (int off = 32; off > 0; off >>= 1)
        s += __shfl_down(s, off, 64);
    if ((tid & 63) == 0) acc[tid >> 6] = s;
    __syncthreads();
    if (tid == 0) {
        float t = 0.f;
#pragma unroll
        for (int k = 0; k < 16; ++k) t += acc[k];
        out[0] = t * scale;
    }
}

extern "C" void kernel_launch(void* const* d_in, const int* in_sizes, int n_in,
                              void* d_out, int out_size, void* d_ws, size_t ws_size,
                              hipStream_t stream) {
    const float* pred   = (const float*)d_in[0];
    const float* target = (const float*)d_in[1];
    const float* weight = (const float*)d_in[2];
    float* out = (float*)d_out;
    float* ws  = (float*)d_ws;
    int N = in_sizes[0] / 5;

    int nblocks = (N + BLOCK - 1) / BLOCK;
    int nparts = nblocks * (BLOCK / 64);
    giou_kernel<<<nblocks, BLOCK, 0, stream>>>(pred, target, weight, ws, N);
    reduce_kernel<<<1, 1024, 0, stream>>>(ws, out, nparts, 1.0f / (float)N);
}